// Round 1
// baseline (308.105 us; speedup 1.0000x reference)
//
#include <hip/hip_runtime.h>
#include <hip/hip_bf16.h>
#include <cstdint>

#define B_ 4
#define SQ_ 128
#define SKV_ 8192
#define H_ 32
#define D_ 128
#define KT 64

typedef __bf16 bf16x8 __attribute__((ext_vector_type(8)));
typedef float f32x4 __attribute__((ext_vector_type(4)));

union U4B8 { uint4 u; bf16x8 v; };

__device__ inline unsigned f2b_pack(float a, float b){
  unsigned ua = __float_as_uint(a); ua = (ua + 0x7FFFu + ((ua >> 16) & 1u)) >> 16;
  unsigned ub = __float_as_uint(b); ub = (ub + 0x7FFFu + ((ub >> 16) & 1u)) >> 16;
  return (ua & 0xFFFFu) | (ub << 16);
}
__device__ inline unsigned short f2b1(float a){
  unsigned ua = __float_as_uint(a);
  return (unsigned short)((ua + 0x7FFFu + ((ua >> 16) & 1u)) >> 16);
}

// Main split-KV attention kernel. Block = 256 threads = 4 waves; each wave owns
// 32 Q rows. Grid = (B*H, nsplit). Writes partial U = sum(e^s * v), l = sum(e^s)
// per split (or the final output directly when nsplit==1).
__global__ __launch_bounds__(256, 2) void mha_split_kernel(
    const float* __restrict__ q, const float* __restrict__ k, const float* __restrict__ v,
    float* __restrict__ Ubase, float* __restrict__ Lbase, float* __restrict__ outp, int nsplit)
{
  __shared__ char smem[48 * 1024] __attribute__((aligned(16)));
  char* Klds = smem;                 // [64][128] bf16, row 256B, swz ^((key&7)<<4)
  char* Vlds = smem + 16 * 1024;     // V^T [128][64] bf16, row 128B, swz ^(((d^(d>>2))&7)<<4)
  char* Plds = smem + 32 * 1024 + (threadIdx.x >> 6) * 4096; // per-wave [32][64] bf16, swz ^((row&7)<<4)

  const int tid = threadIdx.x;
  const int w = tid >> 6;
  const int l = tid & 63;
  const int g = l >> 4;      // 16-lane group 0..3
  const int c = l & 15;      // lane within group
  const int bh = blockIdx.x;
  const int split = blockIdx.y;
  const int b = bh >> 5, h = bh & 31;
  const int kps = SKV_ / nsplit;
  const int kv0 = split * kps;
  const int nt = kps / KT;

  const float qscale = 0.08838834764831845f * 1.4426950408889634f; // 1/sqrt(128) * log2(e)

  // ---- Q fragments in registers (A-operand layout: m = c, k = ks*32 + g*8 + j)
  bf16x8 qf[2][4];
  {
    const float* qp = q + (((size_t)b * SQ_) * H_ + h) * D_;
#pragma unroll
    for (int mi = 0; mi < 2; ++mi) {
      int qrow = w * 32 + mi * 16 + c;
      const float* qr = qp + (size_t)qrow * H_ * D_;
#pragma unroll
      for (int ks = 0; ks < 4; ++ks) {
        int d0 = ks * 32 + g * 8;
        float4 x = *(const float4*)(qr + d0);
        float4 y = *(const float4*)(qr + d0 + 4);
        U4B8 t;
        t.u.x = f2b_pack(x.x * qscale, x.y * qscale);
        t.u.y = f2b_pack(x.z * qscale, x.w * qscale);
        t.u.z = f2b_pack(y.x * qscale, y.y * qscale);
        t.u.w = f2b_pack(y.z * qscale, y.w * qscale);
        qf[mi][ks] = t.v;
      }
    }
  }

  f32x4 oacc[2][8];
#pragma unroll
  for (int mi = 0; mi < 2; ++mi)
#pragma unroll
    for (int ni = 0; ni < 8; ++ni) oacc[mi][ni] = (f32x4)0.0f;
  float lacc[2][4] = {};

  const float* kbase = k + ((size_t)b * SKV_ + kv0) * H_ * D_ + (size_t)h * D_;
  const float* vbase = v + ((size_t)b * SKV_ + kv0) * H_ * D_ + (size_t)h * D_;

  for (int t = 0; t < nt; ++t) {
    // ---- stage K tile [KT][128] fp32 -> bf16 LDS (row-major, swizzled)
    const float* kt = kbase + (size_t)t * KT * H_ * D_;
#pragma unroll
    for (int it = 0; it < 8; ++it) {
      int f = it * 256 + tid;
      int key = f >> 5;
      int d4 = (f & 31) * 4;
      float4 x = *(const float4*)(kt + (size_t)key * (H_ * D_) + d4);
      unsigned lo = f2b_pack(x.x, x.y), hi = f2b_pack(x.z, x.w);
      int off = key * 256 + ((d4 * 2) ^ ((key & 7) << 4));
      *(uint2*)(Klds + off) = make_uint2(lo, hi);
    }
    // ---- stage V tile transposed: V_t[d][key] (pairs of keys packed per b32 write)
    const float* vt = vbase + (size_t)t * KT * H_ * D_;
#pragma unroll
    for (int it = 0; it < 4; ++it) {
      int f = it * 256 + tid;
      int kp = f >> 5;                // key pair index 0..31
      int d4 = (f & 31) * 4;
      const float* va = vt + (size_t)(kp * 2) * (H_ * D_) + d4;
      const float* vb = va + H_ * D_;
      float4 xa = *(const float4*)va;
      float4 xb = *(const float4*)vb;
      float aarr[4] = {xa.x, xa.y, xa.z, xa.w};
      float barr[4] = {xb.x, xb.y, xb.z, xb.w};
#pragma unroll
      for (int i = 0; i < 4; ++i) {
        int d = d4 + i;
        unsigned pk = f2b_pack(aarr[i], barr[i]);
        int off = d * 128 + ((kp * 4) ^ (((d ^ (d >> 2)) & 7) << 4));
        *(unsigned*)(Vlds + off) = pk;
      }
    }
    __syncthreads();

    // ---- S = Q K^T  (per wave: 32 rows x 64 keys)
    f32x4 sacc[2][4];
#pragma unroll
    for (int mi = 0; mi < 2; ++mi)
#pragma unroll
      for (int ni = 0; ni < 4; ++ni) sacc[mi][ni] = (f32x4)0.0f;

#pragma unroll
    for (int ni = 0; ni < 4; ++ni) {
      int key = ni * 16 + c;
      int rb = key * 256;
      int sw = (key & 7) << 4;
#pragma unroll
      for (int ks = 0; ks < 4; ++ks) {
        U4B8 bf;
        bf.u = *(uint4*)(Klds + rb + ((ks * 64 + g * 16) ^ sw));
        sacc[0][ni] = __builtin_amdgcn_mfma_f32_16x16x32_bf16(qf[0][ks], bf.v, sacc[0][ni], 0, 0, 0);
        sacc[1][ni] = __builtin_amdgcn_mfma_f32_16x16x32_bf16(qf[1][ks], bf.v, sacc[1][ni], 0, 0, 0);
      }
    }

    // ---- p = exp2(s'), accumulate row-sum partials, write P (bf16) to wave-private LDS
#pragma unroll
    for (int mi = 0; mi < 2; ++mi) {
#pragma unroll
      for (int ni = 0; ni < 4; ++ni) {
#pragma unroll
        for (int r = 0; r < 4; ++r) {
          float p = exp2f(sacc[mi][ni][r]);
          lacc[mi][r] += p;
          int row = mi * 16 + g * 4 + r;
          int col = ni * 16 + c;
          int off = row * 128 + ((col * 2) ^ ((row & 7) << 4));
          *(unsigned short*)(Plds + off) = f2b1(p);
        }
      }
    }

    // ---- O += P V  (A from P LDS, B from V_t LDS)
#pragma unroll
    for (int ks2 = 0; ks2 < 2; ++ks2) {
      U4B8 ap[2];
#pragma unroll
      for (int mi = 0; mi < 2; ++mi) {
        int row = mi * 16 + c;
        ap[mi].u = *(uint4*)(Plds + row * 128 + ((ks2 * 64 + g * 16) ^ ((row & 7) << 4)));
      }
#pragma unroll
      for (int ni = 0; ni < 8; ++ni) {
        int d = ni * 16 + c;
        U4B8 bv;
        bv.u = *(uint4*)(Vlds + d * 128 + ((ks2 * 64 + g * 16) ^ (((d ^ (d >> 2)) & 7) << 4)));
        oacc[0][ni] = __builtin_amdgcn_mfma_f32_16x16x32_bf16(ap[0].v, bv.v, oacc[0][ni], 0, 0, 0);
        oacc[1][ni] = __builtin_amdgcn_mfma_f32_16x16x32_bf16(ap[1].v, bv.v, oacc[1][ni], 0, 0, 0);
      }
    }
    __syncthreads();
  }

  // ---- reduce l across the 16 lanes that share each row
#pragma unroll
  for (int mi = 0; mi < 2; ++mi) {
#pragma unroll
    for (int r = 0; r < 4; ++r) {
      float s = lacc[mi][r];
      s += __shfl_xor(s, 1, 16);
      s += __shfl_xor(s, 2, 16);
      s += __shfl_xor(s, 4, 16);
      s += __shfl_xor(s, 8, 16);
      lacc[mi][r] = s;
    }
  }

  if (nsplit == 1) {
    float* op = outp + (((size_t)b * SQ_) * H_ + h) * D_;
#pragma unroll
    for (int mi = 0; mi < 2; ++mi) {
#pragma unroll
      for (int r = 0; r < 4; ++r) {
        int row = w * 32 + mi * 16 + g * 4 + r;
        float inv = 1.0f / lacc[mi][r];
#pragma unroll
        for (int ni = 0; ni < 8; ++ni) {
          op[(size_t)row * (H_ * D_) + ni * 16 + c] = oacc[mi][ni][r] * inv;
        }
      }
    }
  } else {
    float* Up = Ubase + ((size_t)split * 128 + bh) * (SQ_ * D_);
#pragma unroll
    for (int mi = 0; mi < 2; ++mi) {
#pragma unroll
      for (int r = 0; r < 4; ++r) {
        int row = w * 32 + mi * 16 + g * 4 + r;
#pragma unroll
        for (int ni = 0; ni < 8; ++ni) {
          Up[(size_t)row * D_ + ni * 16 + c] = oacc[mi][ni][r];
        }
        if (c == 0) Lbase[((size_t)split * 128 + bh) * SQ_ + row] = lacc[mi][r];
      }
    }
  }
}

// Combine kernel: out = sum_s U_s / sum_s l_s, with layout change [b,h,q,d] -> [b,q,h,d]
__global__ void mha_combine_kernel(const float* __restrict__ Ubase, const float* __restrict__ Lbase,
                                   float* __restrict__ outp, int nsplit) {
  int idx = blockIdx.x * 256 + threadIdx.x;   // over BH*SQ*D = 2M
  int rowlin = idx >> 7;                       // bh*128 + row
  int d = idx & 127;
  float su = 0.f, sl = 0.f;
  for (int s = 0; s < nsplit; ++s) {
    su += Ubase[(size_t)s * (128 * SQ_ * D_) + idx];
    sl += Lbase[(size_t)s * (128 * SQ_) + rowlin];
  }
  int bh = rowlin >> 7, row = rowlin & 127;
  int b = bh >> 5, h = bh & 31;
  outp[(((size_t)b * SQ_ + row) * H_ + h) * D_ + d] = su / sl;
}

extern "C" void kernel_launch(void* const* d_in, const int* in_sizes, int n_in,
                              void* d_out, int out_size, void* d_ws, size_t ws_size,
                              hipStream_t stream) {
  const float* q = (const float*)d_in[0];
  const float* k = (const float*)d_in[1];
  const float* v = (const float*)d_in[2];
  float* outp = (float*)d_out;

  const size_t per_split = (size_t)128 * SQ_ * D_ * 4 + (size_t)128 * SQ_ * 4; // U + l per split
  int nsplit = 1;
  if (ws_size >= 4 * per_split) nsplit = 4;
  else if (ws_size >= 2 * per_split) nsplit = 2;

  float* Ubase = (float*)d_ws;
  float* Lbase = Ubase + (size_t)nsplit * 128 * SQ_ * D_;

  dim3 grid(128, nsplit);
  mha_split_kernel<<<grid, 256, 0, stream>>>(q, k, v, Ubase, Lbase, outp, nsplit);
  if (nsplit > 1) {
    mha_combine_kernel<<<(128 * SQ_ * D_) / 256, 256, 0, stream>>>(Ubase, Lbase, outp, nsplit);
  }
}